// Round 1
// baseline (2335.174 us; speedup 1.0000x reference)
//
#include <hip/hip_runtime.h>
#include <cstdio>
#include <cstdint>

// Problem constants: N=8192 tokens, D=256, A=1024, K=65 edge types, E=4096 edges.
#define NTOK 8192
#define DIM  256
#define AA   1024
#define KE   65
#define EE   4096

typedef unsigned short u16;
typedef __attribute__((ext_vector_type(4))) float   f32x4;
typedef __attribute__((ext_vector_type(8))) short   bf16x8;
typedef __attribute__((ext_vector_type(8))) unsigned short u16x8;

#define DEVI __device__ __forceinline__

DEVI u16 f2bf(float f) {               // RNE f32 -> bf16 bits
  union { float f; unsigned u; } x; x.f = f;
  unsigned r = x.u + 0x7FFFu + ((x.u >> 16) & 1u);
  return (u16)(r >> 16);
}
DEVI float bf2f(u16 h) {
  union { unsigned u; float f; } x; x.u = ((unsigned)h) << 16;
  return x.f;
}

DEVI void gload16(const void* g, void* l) {
  // async global->LDS, 16B per lane, LDS dst = wave-uniform base + lane*16
  __builtin_amdgcn_global_load_lds(
      (const __attribute__((address_space(1))) void*)g,
      (__attribute__((address_space(3))) void*)l,
      16, 0, 0);
}

// ---------------------------------------------------------------------------
// Generic 128x128-tile bf16 GEMM, C = A @ B^T.
//   A: (M,K) bf16 row-major, lda
//   B: (N,K) row-major ("B^T layout"): bf16 (BF32=false) or f32 (BF32=true)
// EPI 0: QKV split epilogue (bias add; N in [0,3072): Q | K | V-transposed)
// EPI 1: bf16 store with scale into o_s (ldc)
// EPI 3: edge epilogue: p[row] = sum_col C*Hu, atomicAdd into o_e[row*65+k]
// ---------------------------------------------------------------------------
#define BM 128
#define BN 128
#define BK 64

template<int EPI, bool BF32>
__global__ __launch_bounds__(256)
void gemm_bt(const u16* __restrict__ A, int lda,
             const void* __restrict__ Bptr, int ldb,
             int MT, int NT, int K,
             u16* __restrict__ o_q, u16* __restrict__ o_k, u16* __restrict__ o_vt,
             const float* __restrict__ biasc,
             u16* __restrict__ o_s, float scale, int ldc,
             const u16* __restrict__ Hu, float* __restrict__ o_e)
{
  const int nb  = MT * NT;
  const int per = nb >> 3;                    // grids are multiples of 8
  int bid = blockIdx.x;
  bid = (bid & 7) * per + (bid >> 3);         // XCD-contiguous chunks
  const int mt = bid % MT, nt = bid / MT;     // mt fast => B panel L2 reuse
  const int m0 = mt * BM, n0 = nt * BN;

  __shared__ u16 As[BM * BK];
  __shared__ u16 Bs[BN * BK];

  const int tid  = threadIdx.x;
  const int lane = tid & 63, wave = tid >> 6;
  const int wm = (wave >> 1) * 64, wn = (wave & 1) * 64;

  f32x4 acc[4][4];
#pragma unroll
  for (int m = 0; m < 4; ++m)
#pragma unroll
    for (int n = 0; n < 4; ++n) acc[m][n] = f32x4{0.f, 0.f, 0.f, 0.f};

  const u16*   Bh = (const u16*)Bptr;
  const float* Bf = (const float*)Bptr;

  const int KT = K / BK;
  for (int kt = 0; kt < KT; ++kt) {
    const int k0 = kt * BK;
    // ---- stage A (bf16, async direct-to-LDS) ----
#pragma unroll
    for (int it = 0; it < 4; ++it) {
      int o = it * 4096 + wave * 1024 + lane * 16;   // byte offset in tile
      int r = o >> 7;                                 // 128B per row (64 bf16)
      int c = (o & 127) >> 1;
      gload16(A + (size_t)(m0 + r) * lda + k0 + c,
              &As[(it * 4096 + wave * 1024) >> 1]);
    }
    // ---- stage B ----
    if constexpr (!BF32) {
#pragma unroll
      for (int it = 0; it < 4; ++it) {
        int o = it * 4096 + wave * 1024 + lane * 16;
        int r = o >> 7;
        int c = (o & 127) >> 1;
        gload16(Bh + (size_t)(n0 + r) * ldb + k0 + c,
                &Bs[(it * 4096 + wave * 1024) >> 1]);
      }
    } else {
      // f32 source: reg-stage + convert (can't use global_load_lds)
#pragma unroll
      for (int it = 0; it < 8; ++it) {
        int e = it * 1024 + tid * 4;
        int r = e >> 6, c = e & 63;
        const float4 v = *(const float4*)(Bf + (size_t)(n0 + r) * ldb + k0 + c);
        ushort4 h;
        h.x = f2bf(v.x); h.y = f2bf(v.y); h.z = f2bf(v.z); h.w = f2bf(v.w);
        *(ushort4*)&Bs[r * BK + c] = h;
      }
    }
    asm volatile("s_waitcnt vmcnt(0)" ::: "memory");
    __syncthreads();

    // ---- MFMA on the tile: 2 k-steps of 16 mfma ----
#pragma unroll
    for (int kk = 0; kk < 2; ++kk) {
      const int ro = lane & 15;
      const int ko = kk * 32 + (lane >> 4) * 8;
      bf16x8 af[4], bfg[4];
#pragma unroll
      for (int m = 0; m < 4; ++m)
        af[m] = *(const bf16x8*)&As[(wm + m * 16 + ro) * BK + ko];
#pragma unroll
      for (int n = 0; n < 4; ++n)
        bfg[n] = *(const bf16x8*)&Bs[(wn + n * 16 + ro) * BK + ko];
#pragma unroll
      for (int m = 0; m < 4; ++m)
#pragma unroll
        for (int n = 0; n < 4; ++n)
          acc[m][n] = __builtin_amdgcn_mfma_f32_16x16x32_bf16(
              af[m], bfg[n], acc[m][n], 0, 0, 0);
    }
    __syncthreads();
  }

  // ---- epilogue ----
  const int rgrp = lane >> 4, cid = lane & 15;

  if constexpr (EPI == 0) {
    // QKV: bias add; col<1024 -> Q, <2048 -> K, else V stored transposed
#pragma unroll
    for (int m = 0; m < 4; ++m)
#pragma unroll
      for (int n = 0; n < 4; ++n)
#pragma unroll
        for (int j = 0; j < 4; ++j) {
          int row = m0 + wm + m * 16 + rgrp * 4 + j;
          int col = n0 + wn + n * 16 + cid;
          float v = acc[m][n][j] + biasc[col];
          u16 h = f2bf(v);
          if (col < 1024)       o_q[(size_t)row * AA + col] = h;
          else if (col < 2048)  o_k[(size_t)row * AA + (col - 1024)] = h;
          else                  o_vt[(size_t)(col - 2048) * NTOK + row] = h;
        }
  } else if constexpr (EPI == 1) {
#pragma unroll
    for (int m = 0; m < 4; ++m)
#pragma unroll
      for (int n = 0; n < 4; ++n)
#pragma unroll
        for (int j = 0; j < 4; ++j) {
          int row = m0 + wm + m * 16 + rgrp * 4 + j;
          int col = n0 + wn + n * 16 + cid;
          o_s[(size_t)row * ldc + col] = f2bf(acc[m][n][j] * scale);
        }
  } else {
    // edge: out[e, kidx] += sum_d C[e,d] * Hu[e,d]
    const int kidx  = n0 >> 10;                 // BN=128 stays within one k
    const int dbase = (n0 & 1023) + wn;
#pragma unroll
    for (int m = 0; m < 4; ++m)
#pragma unroll
      for (int j = 0; j < 4; ++j) {
        int row = m0 + wm + m * 16 + rgrp * 4 + j;
        float p = 0.f;
#pragma unroll
        for (int n = 0; n < 4; ++n) {
          int d = dbase + n * 16 + cid;
          p += acc[m][n][j] * bf2f(Hu[(size_t)row * AA + d]);
        }
        p += __shfl_xor(p, 1, 64);
        p += __shfl_xor(p, 2, 64);
        p += __shfl_xor(p, 4, 64);
        p += __shfl_xor(p, 8, 64);
        if (cid == 0) atomicAdd(&o_e[(size_t)row * KE + kidx], p);
      }
  }
}

// ---------------------------------------------------------------------------
// Row softmax over 8192 bf16 columns, in place. One block per row.
// ---------------------------------------------------------------------------
__global__ __launch_bounds__(256)
void softmax_rows(u16* __restrict__ S)
{
  const size_t base = (size_t)blockIdx.x * 8192;
  const int tid = threadIdx.x;
  const int lane = tid & 63, wave = tid >> 6;
  float v[32];
#pragma unroll
  for (int c = 0; c < 4; ++c) {
    u16x8 u = *(const u16x8*)&S[base + c * 2048 + tid * 8];
#pragma unroll
    for (int j = 0; j < 8; ++j) v[c * 8 + j] = bf2f(u[j]);
  }
  float mx = -1e30f;
#pragma unroll
  for (int i = 0; i < 32; ++i) mx = fmaxf(mx, v[i]);
#pragma unroll
  for (int off = 1; off < 64; off <<= 1) mx = fmaxf(mx, __shfl_xor(mx, off, 64));
  __shared__ float r1[4], r2[4];
  if (lane == 0) r1[wave] = mx;
  __syncthreads();
  mx = fmaxf(fmaxf(r1[0], r1[1]), fmaxf(r1[2], r1[3]));

  float s = 0.f;
#pragma unroll
  for (int i = 0; i < 32; ++i) { v[i] = __expf(v[i] - mx); s += v[i]; }
#pragma unroll
  for (int off = 1; off < 64; off <<= 1) s += __shfl_xor(s, off, 64);
  if (lane == 0) r2[wave] = s;
  __syncthreads();
  s = r2[0] + r2[1] + r2[2] + r2[3];
  const float inv = 1.f / s;
#pragma unroll
  for (int c = 0; c < 4; ++c) {
    u16x8 u;
#pragma unroll
    for (int j = 0; j < 8; ++j) u[j] = f2bf(v[c * 8 + j] * inv);
    *(u16x8*)&S[base + c * 2048 + tid * 8] = u;
  }
}

// ---------------------------------------------------------------------------
// Gather Hu/Hv rows from attn_emb. Handles data delivered as int64 OR int32:
// if all sampled odd 32-bit words are zero it's little-endian int64.
// ---------------------------------------------------------------------------
__global__ __launch_bounds__(256)
void gather_rows(const unsigned* __restrict__ dw, const u16* __restrict__ AE,
                 u16* __restrict__ Hu, u16* __restrict__ Hv)
{
  bool i64 = true;
#pragma unroll
  for (int w = 1; w < 32; w += 2) i64 = i64 && (dw[w] == 0u);
  const int e = blockIdx.x;
  const unsigned iu = i64 ? dw[4 * e]     : dw[2 * e];
  const unsigned iv = i64 ? dw[4 * e + 2] : dw[2 * e + 1];
  const int t = threadIdx.x;
  *(ushort4*)&Hu[(size_t)e * AA + t * 4] = *(const ushort4*)&AE[(size_t)iu * AA + t * 4];
  *(ushort4*)&Hv[(size_t)e * AA + t * 4] = *(const ushort4*)&AE[(size_t)iv * AA + t * 4];
}

// zero d_out + build concatenated bias
__global__ __launch_bounds__(256)
void init_misc(float* __restrict__ out_e, const float* __restrict__ bq,
               const float* __restrict__ bk, const float* __restrict__ bv,
               float* __restrict__ biasc)
{
  const int i = blockIdx.x * 256 + threadIdx.x;
  if (i < EE * KE) out_e[i] = 0.f;
  if (i < 1024) {
    biasc[i]        = bq[i];
    biasc[1024 + i] = bk[i];
    biasc[2048 + i] = bv[i];
  }
}

__global__ __launch_bounds__(256)
void cvt_f32_bf16_v4(const float* __restrict__ src, u16* __restrict__ dst, int n4)
{
  const int i = blockIdx.x * 256 + threadIdx.x;
  if (i < n4) {
    float4 v = ((const float4*)src)[i];
    ushort4 h; h.x = f2bf(v.x); h.y = f2bf(v.y); h.z = f2bf(v.z); h.w = f2bf(v.w);
    ((ushort4*)dst)[i] = h;
  }
}

// WqkvT[n][d] = W*(d, n&1023) for n in [0,3072)
__global__ __launch_bounds__(256)
void build_wT(const float* __restrict__ Wq, const float* __restrict__ Wk,
              const float* __restrict__ Wv, u16* __restrict__ WT)
{
  const int nn = blockIdx.x;    // 0..3071
  const int d  = threadIdx.x;   // 0..255
  const float* W = (nn < 1024) ? Wq : ((nn < 2048) ? Wk : Wv);
  WT[nn * DIM + d] = f2bf(W[(size_t)d * AA + (nn & 1023)]);
}

// ---------------------------------------------------------------------------
extern "C" void kernel_launch(void* const* d_in, const int* in_sizes, int n_in,
                              void* d_out, int out_size, void* d_ws, size_t ws_size,
                              hipStream_t stream)
{
  (void)in_sizes; (void)out_size;
  if (n_in < 9) return;
  const float*    emb  = (const float*)d_in[0];
  const unsigned* data = (const unsigned*)d_in[1];
  const float* Wq = (const float*)d_in[2];
  const float* bq = (const float*)d_in[3];
  const float* Wk = (const float*)d_in[4];
  const float* bk = (const float*)d_in[5];
  const float* Wv = (const float*)d_in[6];
  const float* bv = (const float*)d_in[7];
  const float* We = (const float*)d_in[8];
  float* out = (float*)d_out;

  char* ws = (char*)d_ws;
  size_t off = 0;
  auto alloc = [&](size_t bytes) -> void* {
    void* p = ws + off;
    off += (bytes + 255) & ~(size_t)255;
    return p;
  };
  u16*   emb_b = (u16*)alloc((size_t)NTOK * DIM * 2);     //  4.2 MB
  u16*   WT    = (u16*)alloc((size_t)3072 * DIM * 2);     //  1.6 MB
  float* biasc = (float*)alloc(3072 * 4);
  u16*   Qb    = (u16*)alloc((size_t)NTOK * AA * 2);      // 16.8 MB
  u16*   Kb    = (u16*)alloc((size_t)NTOK * AA * 2);
  u16*   Vt    = (u16*)alloc((size_t)AA * NTOK * 2);
  u16*   AE    = (u16*)alloc((size_t)NTOK * AA * 2);
  u16*   Hu    = (u16*)alloc((size_t)EE * AA * 2);        //  8.4 MB
  u16*   Hv    = (u16*)alloc((size_t)EE * AA * 2);

  int chunk = 2048;
  while (chunk > 128 && off + (size_t)chunk * NTOK * 2 > ws_size) chunk >>= 1;
  u16* Sc = (u16*)alloc((size_t)chunk * NTOK * 2);        // 33.5 MB @2048
  if (off > ws_size) {
    fprintf(stderr, "kernel_launch: ws too small (need %zu, have %zu)\n", off, ws_size);
    return;
  }

  init_misc<<<(EE * KE) / 256, 256, 0, stream>>>(out, bq, bk, bv, biasc);
  cvt_f32_bf16_v4<<<(NTOK * DIM / 4) / 256, 256, 0, stream>>>(emb, emb_b, NTOK * DIM / 4);
  build_wT<<<3072, 256, 0, stream>>>(Wq, Wk, Wv, WT);

  // QKV: (8192,3072,256)
  gemm_bt<0, false><<<64 * 24, 256, 0, stream>>>(
      emb_b, DIM, WT, DIM, 64, 24, DIM,
      Qb, Kb, Vt, biasc, nullptr, 0.f, 0, nullptr, nullptr);

  // attention, Q-chunked
  const int nch = NTOK / chunk;
  for (int ci = 0; ci < nch; ++ci) {
    const u16* Qc = Qb + (size_t)ci * chunk * AA;
    gemm_bt<1, false><<<(chunk / 128) * 64, 256, 0, stream>>>(
        Qc, AA, Kb, AA, chunk / 128, 64, AA,
        nullptr, nullptr, nullptr, nullptr, Sc, 0.0625f, NTOK, nullptr, nullptr);
    softmax_rows<<<chunk, 256, 0, stream>>>(Sc);
    gemm_bt<1, false><<<(chunk / 128) * 8, 256, 0, stream>>>(
        Sc, NTOK, Vt, NTOK, chunk / 128, 8, NTOK,
        nullptr, nullptr, nullptr, nullptr,
        AE + (size_t)ci * chunk * AA, 1.0f, AA, nullptr, nullptr);
  }

  gather_rows<<<EE, 256, 0, stream>>>(data, AE, Hu, Hv);

  // edge bilinear: T = Hv @ W_all^T fused with Hu-dot epilogue
  gemm_bt<3, true><<<32 * 520, 256, 0, stream>>>(
      Hv, AA, We, AA, 32, 520, AA,
      nullptr, nullptr, nullptr, nullptr, nullptr, 0.f, 0, Hu, out);
}

// Round 2
// 1759.408 us; speedup vs baseline: 1.3273x; 1.3273x over previous
//
#include <hip/hip_runtime.h>
#include <cstdio>
#include <cstdint>

// Problem constants: N=8192 tokens, D=256, A=1024, K=65 edge types, E=4096 edges.
#define NTOK 8192
#define DIM  256
#define AA   1024
#define KE   65
#define EE   4096

typedef unsigned short u16;
typedef __attribute__((ext_vector_type(4))) float   f32x4;
typedef __attribute__((ext_vector_type(8))) short   bf16x8;
typedef __attribute__((ext_vector_type(8))) unsigned short u16x8;

#define DEVI __device__ __forceinline__

DEVI u16 f2bf(float f) {               // RNE f32 -> bf16 bits
  union { float f; unsigned u; } x; x.f = f;
  unsigned r = x.u + 0x7FFFu + ((x.u >> 16) & 1u);
  return (u16)(r >> 16);
}
DEVI float bf2f(u16 h) {
  union { unsigned u; float f; } x; x.u = ((unsigned)h) << 16;
  return x.f;
}

DEVI void gload16(const void* g, void* l) {
  // async global->LDS, 16B per lane, LDS dst = wave-uniform base + lane*16
  __builtin_amdgcn_global_load_lds(
      (const __attribute__((address_space(1))) void*)g,
      (__attribute__((address_space(3))) void*)l,
      16, 0, 0);
}

// ---------------------------------------------------------------------------
// Generic 128x128-tile bf16 GEMM, C = A @ B^T.
//   A: (M,K) bf16 row-major, lda
//   B: (N,K) row-major ("B^T layout"): bf16 (BF32=false) or f32 (BF32=true)
// EPI 0: QKV split epilogue (bias add; N in [0,3072): Q | K | V-transposed)
// EPI 1: bf16 store with scale into o_s (ldc)
// EPI 3: edge epilogue: p[row] = sum_col C*Hu, atomicAdd into o_e[row*65+k]
// ---------------------------------------------------------------------------
#define BM 128
#define BN 128
#define BK 64

template<int EPI, bool BF32>
__global__ __launch_bounds__(256)
void gemm_bt(const u16* __restrict__ A, int lda,
             const void* __restrict__ Bptr, int ldb,
             int MT, int NT, int K,
             u16* __restrict__ o_q, u16* __restrict__ o_k, u16* __restrict__ o_vt,
             const float* __restrict__ biasc,
             u16* __restrict__ o_s, float scale, int ldc,
             const u16* __restrict__ Hu, float* __restrict__ o_e)
{
  const int nb  = MT * NT;
  const int per = nb >> 3;                    // grids are multiples of 8
  int bid = blockIdx.x;
  bid = (bid & 7) * per + (bid >> 3);         // XCD-contiguous chunks
  const int mt = bid % MT, nt = bid / MT;     // mt fast => B panel L2 reuse
  const int m0 = mt * BM, n0 = nt * BN;

  __shared__ u16 As[BM * BK];
  __shared__ u16 Bs[BN * BK];

  const int tid  = threadIdx.x;
  const int lane = tid & 63, wave = tid >> 6;
  const int wm = (wave >> 1) * 64, wn = (wave & 1) * 64;

  f32x4 acc[4][4];
#pragma unroll
  for (int m = 0; m < 4; ++m)
#pragma unroll
    for (int n = 0; n < 4; ++n) acc[m][n] = f32x4{0.f, 0.f, 0.f, 0.f};

  const u16*   Bh = (const u16*)Bptr;
  const float* Bf = (const float*)Bptr;

  const int KT = K / BK;
  for (int kt = 0; kt < KT; ++kt) {
    const int k0 = kt * BK;
    // ---- stage A (bf16, async direct-to-LDS) ----
#pragma unroll
    for (int it = 0; it < 4; ++it) {
      int o = it * 4096 + wave * 1024 + lane * 16;   // byte offset in tile
      int r = o >> 7;                                 // 128B per row (64 bf16)
      int c = (o & 127) >> 1;
      gload16(A + (size_t)(m0 + r) * lda + k0 + c,
              &As[(it * 4096 + wave * 1024) >> 1]);
    }
    // ---- stage B ----
    if constexpr (!BF32) {
#pragma unroll
      for (int it = 0; it < 4; ++it) {
        int o = it * 4096 + wave * 1024 + lane * 16;
        int r = o >> 7;
        int c = (o & 127) >> 1;
        gload16(Bh + (size_t)(n0 + r) * ldb + k0 + c,
                &Bs[(it * 4096 + wave * 1024) >> 1]);
      }
    } else {
      // f32 source: reg-stage + convert (can't use global_load_lds)
#pragma unroll
      for (int it = 0; it < 8; ++it) {
        int e = it * 1024 + tid * 4;
        int r = e >> 6, c = e & 63;
        const float4 v = *(const float4*)(Bf + (size_t)(n0 + r) * ldb + k0 + c);
        ushort4 h;
        h.x = f2bf(v.x); h.y = f2bf(v.y); h.z = f2bf(v.z); h.w = f2bf(v.w);
        *(ushort4*)&Bs[r * BK + c] = h;
      }
    }
    asm volatile("s_waitcnt vmcnt(0)" ::: "memory");
    __syncthreads();

    // ---- MFMA on the tile: 2 k-steps of 16 mfma ----
#pragma unroll
    for (int kk = 0; kk < 2; ++kk) {
      const int ro = lane & 15;
      const int ko = kk * 32 + (lane >> 4) * 8;
      bf16x8 af[4], bfg[4];
#pragma unroll
      for (int m = 0; m < 4; ++m)
        af[m] = *(const bf16x8*)&As[(wm + m * 16 + ro) * BK + ko];
#pragma unroll
      for (int n = 0; n < 4; ++n)
        bfg[n] = *(const bf16x8*)&Bs[(wn + n * 16 + ro) * BK + ko];
#pragma unroll
      for (int m = 0; m < 4; ++m)
#pragma unroll
        for (int n = 0; n < 4; ++n)
          acc[m][n] = __builtin_amdgcn_mfma_f32_16x16x32_bf16(
              af[m], bfg[n], acc[m][n], 0, 0, 0);
    }
    __syncthreads();
  }

  // ---- epilogue ----
  const int rgrp = lane >> 4, cid = lane & 15;

  if constexpr (EPI == 0) {
    // QKV: bias add; col<1024 -> Q, <2048 -> K, else V stored transposed
#pragma unroll
    for (int m = 0; m < 4; ++m)
#pragma unroll
      for (int n = 0; n < 4; ++n)
#pragma unroll
        for (int j = 0; j < 4; ++j) {
          int row = m0 + wm + m * 16 + rgrp * 4 + j;
          int col = n0 + wn + n * 16 + cid;
          float v = acc[m][n][j] + biasc[col];
          u16 h = f2bf(v);
          if (col < 1024)       o_q[(size_t)row * AA + col] = h;
          else if (col < 2048)  o_k[(size_t)row * AA + (col - 1024)] = h;
          else                  o_vt[(size_t)(col - 2048) * NTOK + row] = h;
        }
  } else if constexpr (EPI == 1) {
#pragma unroll
    for (int m = 0; m < 4; ++m)
#pragma unroll
      for (int n = 0; n < 4; ++n)
#pragma unroll
        for (int j = 0; j < 4; ++j) {
          int row = m0 + wm + m * 16 + rgrp * 4 + j;
          int col = n0 + wn + n * 16 + cid;
          o_s[(size_t)row * ldc + col] = f2bf(acc[m][n][j] * scale);
        }
  } else {
    // edge: out[e, kidx] += sum_d C[e,d] * Hu[e,d]
    const int kidx  = n0 >> 10;                 // BN=128 stays within one k
    const int dbase = (n0 & 1023) + wn;
#pragma unroll
    for (int m = 0; m < 4; ++m)
#pragma unroll
      for (int j = 0; j < 4; ++j) {
        int row = m0 + wm + m * 16 + rgrp * 4 + j;
        float p = 0.f;
#pragma unroll
        for (int n = 0; n < 4; ++n) {
          int d = dbase + n * 16 + cid;
          p += acc[m][n][j] * bf2f(Hu[(size_t)row * AA + d]);
        }
        p += __shfl_xor(p, 1, 64);
        p += __shfl_xor(p, 2, 64);
        p += __shfl_xor(p, 4, 64);
        p += __shfl_xor(p, 8, 64);
        if (cid == 0) atomicAdd(&o_e[(size_t)row * KE + kidx], p);
      }
  }
}

// ---------------------------------------------------------------------------
// Row softmax over 8192 bf16 columns, in place. One block per row.
// ---------------------------------------------------------------------------
__global__ __launch_bounds__(256)
void softmax_rows(u16* __restrict__ S)
{
  const size_t base = (size_t)blockIdx.x * 8192;
  const int tid = threadIdx.x;
  const int lane = tid & 63, wave = tid >> 6;
  float v[32];
#pragma unroll
  for (int c = 0; c < 4; ++c) {
    u16x8 u = *(const u16x8*)&S[base + c * 2048 + tid * 8];
#pragma unroll
    for (int j = 0; j < 8; ++j) v[c * 8 + j] = bf2f(u[j]);
  }
  float mx = -1e30f;
#pragma unroll
  for (int i = 0; i < 32; ++i) mx = fmaxf(mx, v[i]);
#pragma unroll
  for (int off = 1; off < 64; off <<= 1) mx = fmaxf(mx, __shfl_xor(mx, off, 64));
  __shared__ float r1[4], r2[4];
  if (lane == 0) r1[wave] = mx;
  __syncthreads();
  mx = fmaxf(fmaxf(r1[0], r1[1]), fmaxf(r1[2], r1[3]));

  float s = 0.f;
#pragma unroll
  for (int i = 0; i < 32; ++i) { v[i] = __expf(v[i] - mx); s += v[i]; }
#pragma unroll
  for (int off = 1; off < 64; off <<= 1) s += __shfl_xor(s, off, 64);
  if (lane == 0) r2[wave] = s;
  __syncthreads();
  s = r2[0] + r2[1] + r2[2] + r2[3];
  const float inv = 1.f / s;
#pragma unroll
  for (int c = 0; c < 4; ++c) {
    u16x8 u;
#pragma unroll
    for (int j = 0; j < 8; ++j) u[j] = f2bf(v[c * 8 + j] * inv);
    *(u16x8*)&S[base + c * 2048 + tid * 8] = u;
  }
}

// ---------------------------------------------------------------------------
// Gather Hu/Hv rows from attn_emb. Handles data delivered as int64 OR int32:
// if all sampled odd 32-bit words are zero it's little-endian int64.
// ---------------------------------------------------------------------------
__global__ __launch_bounds__(256)
void gather_rows(const unsigned* __restrict__ dw, const u16* __restrict__ AE,
                 u16* __restrict__ Hu, u16* __restrict__ Hv)
{
  bool i64 = true;
#pragma unroll
  for (int w = 1; w < 32; w += 2) i64 = i64 && (dw[w] == 0u);
  const int e = blockIdx.x;
  const unsigned iu = i64 ? dw[4 * e]     : dw[2 * e];
  const unsigned iv = i64 ? dw[4 * e + 2] : dw[2 * e + 1];
  const int t = threadIdx.x;
  *(ushort4*)&Hu[(size_t)e * AA + t * 4] = *(const ushort4*)&AE[(size_t)iu * AA + t * 4];
  *(ushort4*)&Hv[(size_t)e * AA + t * 4] = *(const ushort4*)&AE[(size_t)iv * AA + t * 4];
}

// zero d_out + build concatenated bias
__global__ __launch_bounds__(256)
void init_misc(float* __restrict__ out_e, const float* __restrict__ bq,
               const float* __restrict__ bk, const float* __restrict__ bv,
               float* __restrict__ biasc)
{
  const int i = blockIdx.x * 256 + threadIdx.x;
  if (i < EE * KE) out_e[i] = 0.f;
  if (i < 1024) {
    biasc[i]        = bq[i];
    biasc[1024 + i] = bk[i];
    biasc[2048 + i] = bv[i];
  }
}

// grid-stride f32 -> bf16 conversion, float4 granularity
__global__ __launch_bounds__(256)
void cvt_f32_bf16_v4(const float* __restrict__ src, u16* __restrict__ dst, int n4)
{
  for (int i = blockIdx.x * 256 + threadIdx.x; i < n4; i += gridDim.x * 256) {
    float4 v = ((const float4*)src)[i];
    ushort4 h; h.x = f2bf(v.x); h.y = f2bf(v.y); h.z = f2bf(v.z); h.w = f2bf(v.w);
    ((ushort4*)dst)[i] = h;
  }
}

// WqkvT[n][d] = W*(d, n&1023) for n in [0,3072)
__global__ __launch_bounds__(256)
void build_wT(const float* __restrict__ Wq, const float* __restrict__ Wk,
              const float* __restrict__ Wv, u16* __restrict__ WT)
{
  const int nn = blockIdx.x;    // 0..3071
  const int d  = threadIdx.x;   // 0..255
  const float* W = (nn < 1024) ? Wq : ((nn < 2048) ? Wk : Wv);
  WT[nn * DIM + d] = f2bf(W[(size_t)d * AA + (nn & 1023)]);
}

// ---------------------------------------------------------------------------
extern "C" void kernel_launch(void* const* d_in, const int* in_sizes, int n_in,
                              void* d_out, int out_size, void* d_ws, size_t ws_size,
                              hipStream_t stream)
{
  (void)in_sizes; (void)out_size;
  if (n_in < 9) return;
  const float*    emb  = (const float*)d_in[0];
  const unsigned* data = (const unsigned*)d_in[1];
  const float* Wq = (const float*)d_in[2];
  const float* bq = (const float*)d_in[3];
  const float* Wk = (const float*)d_in[4];
  const float* bk = (const float*)d_in[5];
  const float* Wv = (const float*)d_in[6];
  const float* bv = (const float*)d_in[7];
  const float* We = (const float*)d_in[8];
  float* out = (float*)d_out;

  char* ws = (char*)d_ws;
  size_t off = 0;
  auto alloc = [&](size_t bytes) -> void* {
    void* p = ws + off;
    off += (bytes + 255) & ~(size_t)255;
    return p;
  };
  u16*   emb_b = (u16*)alloc((size_t)NTOK * DIM * 2);     //  4.2 MB
  u16*   WT    = (u16*)alloc((size_t)3072 * DIM * 2);     //  1.6 MB
  float* biasc = (float*)alloc(3072 * 4);
  u16*   Qb    = (u16*)alloc((size_t)NTOK * AA * 2);      // 16.8 MB
  u16*   Kb    = (u16*)alloc((size_t)NTOK * AA * 2);
  u16*   Vt    = (u16*)alloc((size_t)AA * NTOK * 2);
  u16*   AE    = (u16*)alloc((size_t)NTOK * AA * 2);
  u16*   Hu    = (u16*)alloc((size_t)EE * AA * 2);        //  8.4 MB
  u16*   Hv    = (u16*)alloc((size_t)EE * AA * 2);

  // Optional bf16 copy of W_edge (136 MB) — only if it leaves room for a
  // reasonable score chunk. Fallback: f32 reg-stage path (round-1 behavior).
  const size_t webf_bytes = ((size_t)KE * AA * AA * 2 + 255) & ~(size_t)255;
  u16* We_b = nullptr;
  if (off + webf_bytes + (size_t)1024 * NTOK * 2 <= ws_size) {
    We_b = (u16*)(ws + off);
    off += webf_bytes;
  }

  int chunk = NTOK;  // prefer one full pass: PV GEMM gets 512 blocks (2/CU)
  while (chunk > 128 && off + (size_t)chunk * NTOK * 2 > ws_size) chunk >>= 1;
  u16* Sc = (u16*)alloc((size_t)chunk * NTOK * 2);
  if (off > ws_size) {
    fprintf(stderr, "kernel_launch: ws too small (need %zu, have %zu)\n", off, ws_size);
    return;
  }

  init_misc<<<(EE * KE) / 256, 256, 0, stream>>>(out, bq, bk, bv, biasc);
  cvt_f32_bf16_v4<<<2048, 256, 0, stream>>>(emb, emb_b, NTOK * DIM / 4);
  build_wT<<<3072, 256, 0, stream>>>(Wq, Wk, Wv, WT);
  if (We_b)
    cvt_f32_bf16_v4<<<4096, 256, 0, stream>>>(We, We_b, KE * AA * AA / 4);

  // QKV: (8192,3072,256)
  gemm_bt<0, false><<<64 * 24, 256, 0, stream>>>(
      emb_b, DIM, WT, DIM, 64, 24, DIM,
      Qb, Kb, Vt, biasc, nullptr, 0.f, 0, nullptr, nullptr);

  // attention, Q-chunked (chunk == NTOK -> single pass)
  const int nch = NTOK / chunk;
  for (int ci = 0; ci < nch; ++ci) {
    const u16* Qc = Qb + (size_t)ci * chunk * AA;
    gemm_bt<1, false><<<(chunk / 128) * 64, 256, 0, stream>>>(
        Qc, AA, Kb, AA, chunk / 128, 64, AA,
        nullptr, nullptr, nullptr, nullptr, Sc, 0.0625f, NTOK, nullptr, nullptr);
    softmax_rows<<<chunk, 256, 0, stream>>>(Sc);
    gemm_bt<1, false><<<(chunk / 128) * 8, 256, 0, stream>>>(
        Sc, NTOK, Vt, NTOK, chunk / 128, 8, NTOK,
        nullptr, nullptr, nullptr, nullptr,
        AE + (size_t)ci * chunk * AA, 1.0f, AA, nullptr, nullptr);
  }

  gather_rows<<<EE, 256, 0, stream>>>(data, AE, Hu, Hv);

  // edge bilinear: T = Hv @ W_all^T fused with Hu-dot epilogue
  if (We_b)
    gemm_bt<3, false><<<32 * 520, 256, 0, stream>>>(
        Hv, AA, We_b, AA, 32, 520, AA,
        nullptr, nullptr, nullptr, nullptr, nullptr, 0.f, 0, Hu, out);
  else
    gemm_bt<3, true><<<32 * 520, 256, 0, stream>>>(
        Hv, AA, We, AA, 32, 520, AA,
        nullptr, nullptr, nullptr, nullptr, nullptr, 0.f, 0, Hu, out);
}